// Round 6
// baseline (753.824 us; speedup 1.0000x reference)
//
#include <hip/hip_runtime.h>
#include <math.h>

typedef __bf16 bf16;
typedef __attribute__((ext_vector_type(8))) __bf16 bf16x8;
typedef __attribute__((ext_vector_type(4))) __bf16 bf16x4;
typedef __attribute__((ext_vector_type(4))) float floatx4;

#define MFMA16(a, b, c) __builtin_amdgcn_mfma_f32_16x16x32_bf16((a), (b), (c), 0, 0, 0)

__device__ __forceinline__ float bflo(unsigned d) {
    unsigned u = d << 16; float f; __builtin_memcpy(&f, &u, 4); return f;
}
__device__ __forceinline__ float bfhi(unsigned d) {
    unsigned u = d & 0xffff0000u; float f; __builtin_memcpy(&f, &u, 4); return f;
}

__device__ __forceinline__ void breduce1(float &a, float* lds, int t) {
    #pragma unroll
    for (int off = 32; off; off >>= 1) a += __shfl_xor(a, off, 64);
    __syncthreads();
    if ((t & 63) == 0) lds[t >> 6] = a;
    __syncthreads();
    a = lds[0] + lds[1] + lds[2] + lds[3];
}

// ---------------- init: copy res lower half --------------------------------
__global__ __launch_bounds__(256) void init_kernel(const float* __restrict__ x0,
                                                   float* __restrict__ out) {
    int fi = blockIdx.x * 256 + threadIdx.x;
    int b = fi >> 18;
    int r = fi & 262143;
    const float4* src = (const float4*)x0;
    float4* dst = (float4*)out;
    dst[(size_t)b * 524288 + r] = src[(size_t)b * 524288 + r];
}

// ---------------- weight fp32 -> bf16 hi/lo pairs (8 matrices) -------------
__global__ __launch_bounds__(256) void wconv(
    const float* __restrict__ w0, const float* __restrict__ w1,
    const float* __restrict__ w2, const float* __restrict__ w3,
    const float* __restrict__ w4, const float* __restrict__ w5,
    const float* __restrict__ w6, const float* __restrict__ w7,
    bf16* __restrict__ dst) {
    const int wi = blockIdx.y;
    const float* src = wi == 0 ? w0 : wi == 1 ? w1 : wi == 2 ? w2 : wi == 3 ? w3
                     : wi == 4 ? w4 : wi == 5 ? w5 : wi == 6 ? w6 : w7;
    const int i = blockIdx.x * 1024 + threadIdx.x * 4;
    const float4 v = *(const float4*)(src + i);
    bf16x4 h, l;
    #pragma unroll
    for (int j = 0; j < 4; j++) {
        const float f = ((const float*)&v)[j];
        const bf16 hb = (bf16)f;
        h[j] = hb;
        l[j] = (bf16)(f - (float)hb);
    }
    *(bf16x4*)(dst + (size_t)wi * 65536 + i) = h;
    *(bf16x4*)(dst + (size_t)(8 + wi) * 65536 + i) = l;
}

// ---------------- split-precision MFMA GEMM --------------------------------
// D[n][o] = A[n][k] * W[o][k]^T + bias.  tile 128n x 128o, K=256 in 8x32.
// MODE 0: A fp32 [k][n] staged+split; out q fp32 + qbfT bf16.
// MODE 3: A bf16 [n][k]; out s fp32 (upper half).
// MODE 4: A bf16 [n][k]; fused res = x0*exp(s)+t write + jac partial.
template <int MODE>
__global__ __launch_bounds__(256) void gemm_mfma(
    const void* __restrict__ Aptr, int ldA, long long bsA,
    const bf16* __restrict__ Whi, const bf16* __restrict__ Wlo,
    const float* __restrict__ bias,
    bf16* __restrict__ outb,
    float* outf,
    const float* __restrict__ x0full,
    float* __restrict__ jpart)
{
    constexpr bool ASPLIT = (MODE <= 2);
    __shared__ __align__(16) bf16 As_hi[128 * 40];
    __shared__ __align__(16) bf16 As_lo[ASPLIT ? 128 * 40 : 1];
    __shared__ __align__(16) bf16 Bs_hi[128 * 40];
    __shared__ __align__(16) bf16 Bs_lo[128 * 40];
    __shared__ float red[4];
    const int t = threadIdx.x;
    const int b = blockIdx.z;
    const int n0 = blockIdx.x * 128;
    const int o0 = blockIdx.y * 128;
    const int w = t >> 6, l = t & 63;
    const int wr = w & 1, wc = w >> 1;
    const int lr = l & 15, lq = l >> 4;

    floatx4 acc[4][4] = {};

    for (int kb = 0; kb < 8; kb++) {
        if (ASPLIT) {
            const float* Af = (const float*)Aptr + (size_t)b * bsA;
            #pragma unroll
            for (int s = 0; s < 4; s++) {
                const int kk = s * 8 + (t >> 5);
                const int n = (t & 31) * 4;
                const float4 v = *(const float4*)(Af + (size_t)(kb * 32 + kk) * ldA + n0 + n);
                #pragma unroll
                for (int j = 0; j < 4; j++) {
                    const float f = ((const float*)&v)[j];
                    const bf16 hb = (bf16)f;
                    As_hi[(n + j) * 40 + kk] = hb;
                    As_lo[(n + j) * 40 + kk] = (bf16)(f - (float)hb);
                }
            }
        } else {
            const bf16* Ab = (const bf16*)Aptr + (size_t)b * bsA;
            #pragma unroll
            for (int s = 0; s < 2; s++) {
                const int idx = t + 256 * s;
                const int row = idx >> 2, seg = idx & 3;
                *(bf16x8*)(As_hi + row * 40 + seg * 8) =
                    *(const bf16x8*)(Ab + (size_t)(n0 + row) * 256 + kb * 32 + seg * 8);
            }
        }
        #pragma unroll
        for (int s = 0; s < 2; s++) {
            const int idx = t + 256 * s;
            const int row = idx >> 2, seg = idx & 3;
            *(bf16x8*)(Bs_hi + row * 40 + seg * 8) =
                *(const bf16x8*)(Whi + (size_t)(o0 + row) * 256 + kb * 32 + seg * 8);
            *(bf16x8*)(Bs_lo + row * 40 + seg * 8) =
                *(const bf16x8*)(Wlo + (size_t)(o0 + row) * 256 + kb * 32 + seg * 8);
        }
        __syncthreads();
        bf16x8 ah[4], al[4], bh[4], bl[4];
        #pragma unroll
        for (int f = 0; f < 4; f++) {
            ah[f] = *(const bf16x8*)(As_hi + (wr * 64 + f * 16 + lr) * 40 + lq * 8);
            if (ASPLIT)
                al[f] = *(const bf16x8*)(As_lo + (wr * 64 + f * 16 + lr) * 40 + lq * 8);
            bh[f] = *(const bf16x8*)(Bs_hi + (wc * 64 + f * 16 + lr) * 40 + lq * 8);
            bl[f] = *(const bf16x8*)(Bs_lo + (wc * 64 + f * 16 + lr) * 40 + lq * 8);
        }
        #pragma unroll
        for (int i = 0; i < 4; i++)
            #pragma unroll
            for (int j = 0; j < 4; j++) {
                acc[i][j] = MFMA16(ah[i], bh[j], acc[i][j]);
                acc[i][j] = MFMA16(ah[i], bl[j], acc[i][j]);
                if (ASPLIT) acc[i][j] = MFMA16(al[i], bh[j], acc[i][j]);
            }
        __syncthreads();
    }

    float ssum = 0.0f;
    #pragma unroll
    for (int i = 0; i < 4; i++) {
        #pragma unroll
        for (int j = 0; j < 4; j++) {
            const int o_g = o0 + wc * 64 + j * 16 + lr;
            const int n_b = n0 + wr * 64 + i * 16 + lq * 4;
            const float bia = bias[o_g];
            floatx4 val = acc[i][j];
            val[0] += bia; val[1] += bia; val[2] += bia; val[3] += bia;
            if (MODE == 0) {
                *(floatx4*)(outf + (size_t)b * 2097152 + (size_t)o_g * 4096 + n_b) = val;
                #pragma unroll
                for (int r = 0; r < 4; r++)
                    outb[((size_t)b * 4096 + n_b + r) * 256 + o_g] = (bf16)val[r];
            } else {
                const size_t addr = (size_t)b * 2097152 + (size_t)(256 + o_g) * 4096 + n_b;
                if (MODE == 3) {
                    *(floatx4*)(outf + addr) = val;
                } else {
                    const floatx4 s4 = *(const floatx4*)(outf + addr);
                    const floatx4 x4 = *(const floatx4*)(x0full + addr);
                    floatx4 res;
                    #pragma unroll
                    for (int r = 0; r < 4; r++) res[r] = x4[r] * expf(s4[r]) + val[r];
                    *(floatx4*)(outf + addr) = res;
                    ssum += s4[0] + s4[1] + s4[2] + s4[3];
                }
            }
        }
    }
    if (MODE == 4) {
        breduce1(ssum, red, t);
        if (t == 0) jpart[b * 64 + blockIdx.y * 32 + blockIdx.x] = ssum;
    }
}

// ---------------- merged K+V GEMM (pre-split bf16 A) -----------------------
// A = xs hi/lo [b][n 256][c 256].  grid (2 n-tiles, 4 = {K:o0,K:o1,V:o0,V:o1}, 8 b)
__global__ __launch_bounds__(256) void gemm_kv(
    const bf16* __restrict__ xs_hi, const bf16* __restrict__ xs_lo,
    const bf16* __restrict__ wkh, const bf16* __restrict__ wkl,
    const bf16* __restrict__ wvh, const bf16* __restrict__ wvl,
    const float* __restrict__ bk, const float* __restrict__ bv,
    bf16* __restrict__ kT, bf16* __restrict__ vbuf)
{
    __shared__ __align__(16) bf16 As_hi[128 * 40];
    __shared__ __align__(16) bf16 As_lo[128 * 40];
    __shared__ __align__(16) bf16 Bs_hi[128 * 40];
    __shared__ __align__(16) bf16 Bs_lo[128 * 40];
    const int t = threadIdx.x;
    const int b = blockIdx.z;
    const int n0 = blockIdx.x * 128;
    const int kv = blockIdx.y >> 1;
    const int o0 = (blockIdx.y & 1) * 128;
    const bf16* Whi = kv ? wvh : wkh;
    const bf16* Wlo = kv ? wvl : wkl;
    const float* bias = kv ? bv : bk;
    const int w = t >> 6, l = t & 63;
    const int wr = w & 1, wc = w >> 1;
    const int lr = l & 15, lq = l >> 4;

    floatx4 acc[4][4] = {};

    for (int kb = 0; kb < 8; kb++) {
        #pragma unroll
        for (int s = 0; s < 2; s++) {
            const int idx = t + 256 * s;
            const int row = idx >> 2, seg = idx & 3;
            const size_t asrc = ((size_t)b * 256 + n0 + row) * 256 + kb * 32 + seg * 8;
            *(bf16x8*)(As_hi + row * 40 + seg * 8) = *(const bf16x8*)(xs_hi + asrc);
            *(bf16x8*)(As_lo + row * 40 + seg * 8) = *(const bf16x8*)(xs_lo + asrc);
            *(bf16x8*)(Bs_hi + row * 40 + seg * 8) =
                *(const bf16x8*)(Whi + (size_t)(o0 + row) * 256 + kb * 32 + seg * 8);
            *(bf16x8*)(Bs_lo + row * 40 + seg * 8) =
                *(const bf16x8*)(Wlo + (size_t)(o0 + row) * 256 + kb * 32 + seg * 8);
        }
        __syncthreads();
        bf16x8 ah[4], al[4], bh[4], bl[4];
        #pragma unroll
        for (int f = 0; f < 4; f++) {
            ah[f] = *(const bf16x8*)(As_hi + (wr * 64 + f * 16 + lr) * 40 + lq * 8);
            al[f] = *(const bf16x8*)(As_lo + (wr * 64 + f * 16 + lr) * 40 + lq * 8);
            bh[f] = *(const bf16x8*)(Bs_hi + (wc * 64 + f * 16 + lr) * 40 + lq * 8);
            bl[f] = *(const bf16x8*)(Bs_lo + (wc * 64 + f * 16 + lr) * 40 + lq * 8);
        }
        #pragma unroll
        for (int i = 0; i < 4; i++)
            #pragma unroll
            for (int j = 0; j < 4; j++) {
                acc[i][j] = MFMA16(ah[i], bh[j], acc[i][j]);
                acc[i][j] = MFMA16(ah[i], bl[j], acc[i][j]);
                acc[i][j] = MFMA16(al[i], bh[j], acc[i][j]);
            }
        __syncthreads();
    }

    #pragma unroll
    for (int i = 0; i < 4; i++) {
        #pragma unroll
        for (int j = 0; j < 4; j++) {
            const int o_g = o0 + wc * 64 + j * 16 + lr;
            const int n_b = n0 + wr * 64 + i * 16 + lq * 4;
            const float bia = bias[o_g];
            floatx4 val = acc[i][j];
            val[0] += bia; val[1] += bia; val[2] += bia; val[3] += bia;
            if (kv == 0) {
                #pragma unroll
                for (int r = 0; r < 4; r++)
                    kT[((size_t)b * 256 + n_b + r) * 256 + o_g] = (bf16)val[r];
            } else {
                bf16x4 pv;
                pv[0] = (bf16)val[0]; pv[1] = (bf16)val[1];
                pv[2] = (bf16)val[2]; pv[3] = (bf16)val[3];
                *(bf16x4*)(vbuf + ((size_t)b * 256 + o_g) * 256 + n_b) = pv;
            }
        }
    }
}

// ---------------- jac finalize ---------------------------------------------
__global__ __launch_bounds__(64) void jac_reduce(const float* __restrict__ jpart,
                                                 float* __restrict__ out) {
    const int b = blockIdx.x, t = threadIdx.x;
    float v = jpart[b * 64 + t];
    #pragma unroll
    for (int off = 32; off; off >>= 1) v += __shfl_xor(v, off, 64);
    if (t == 0) out[16777216 + b] = v;
}

// ---------------- offset branch (q fp32 lives in out-lower) ----------------
__global__ __launch_bounds__(256) void offset_kernel(
    const float* __restrict__ q,
    const float* __restrict__ dw_w, const float* __restrict__ dw_b,
    const float* __restrict__ ln_g, const float* __restrict__ ln_b,
    const float* __restrict__ pw_w,
    float* __restrict__ pos)
{
    __shared__ float red[8];
    const int wk = blockIdx.x, hk = blockIdx.y, b = blockIdx.z;
    const int c = threadIdx.x;
    const float* qp = q + (size_t)b * 2097152 + (size_t)c * 4096 + (hk * 4) * 64 + wk * 4;
    float accv = dw_b[c];
    #pragma unroll
    for (int p = 0; p < 4; p++) {
        const float4 r = *(const float4*)(qp + p * 64);
        const float4 w = *(const float4*)(dw_w + c * 16 + p * 4);
        accv += r.x * w.x + r.y * w.y + r.z * w.z + r.w * w.w;
    }
    float a = accv, sq = accv * accv;
    #pragma unroll
    for (int off = 32; off; off >>= 1) {
        a += __shfl_xor(a, off, 64);
        sq += __shfl_xor(sq, off, 64);
    }
    __syncthreads();
    if ((c & 63) == 0) { red[c >> 6] = a; red[4 + (c >> 6)] = sq; }
    __syncthreads();
    a = red[0] + red[1] + red[2] + red[3];
    sq = red[4] + red[5] + red[6] + red[7];
    const float mu = a * (1.0f / 256.0f);
    const float var = sq * (1.0f / 256.0f) - mu * mu;
    float nrm = (accv - mu) * rsqrtf(var + 1e-5f) * ln_g[c] + ln_b[c];
    const float act = 0.5f * nrm * (1.0f + erff(nrm * 0.70710678118654752f));
    float v0 = pw_w[c] * act;
    float v1 = pw_w[256 + c] * act;
    #pragma unroll
    for (int off = 32; off; off >>= 1) {
        v0 += __shfl_xor(v0, off, 64);
        v1 += __shfl_xor(v1, off, 64);
    }
    __syncthreads();
    if ((c & 63) == 0) { red[c >> 6] = v0; red[4 + (c >> 6)] = v1; }
    __syncthreads();
    if (c == 0) {
        v0 = red[0] + red[1] + red[2] + red[3];
        v1 = red[4] + red[5] + red[6] + red[7];
        const float refy = (0.5f + hk) * (2.0f / 15.0f) - 1.0f;
        const float refx = (0.5f + wk) * (2.0f / 15.0f) - 1.0f;
        const float py = fminf(fmaxf(v0 + refy, -1.0f), 1.0f);
        const float px = fminf(fmaxf(v1 + refx, -1.0f), 1.0f);
        const int n = hk * 16 + wk;
        pos[(b * 256 + n) * 2] = py;
        pos[(b * 256 + n) * 2 + 1] = px;
    }
}

// ---------------- bilinear sample -> xs bf16 hi/lo [b][n][c] ---------------
__global__ __launch_bounds__(256) void sample_kernel(
    const float* __restrict__ x0,
    const float* __restrict__ pos,
    bf16* __restrict__ xs_hi,
    bf16* __restrict__ xs_lo)
{
    const int c = threadIdx.x, n = blockIdx.x, b = blockIdx.y;
    const float py = pos[(b * 256 + n) * 2];
    const float px = pos[(b * 256 + n) * 2 + 1];
    const float x = (px + 1.0f) * 31.5f;
    const float y = (py + 1.0f) * 31.5f;
    const float xf = floorf(x), yf = floorf(y);
    const float wx = x - xf, wy = y - yf;
    const int xi0 = min(max((int)xf, 0), 63);
    const int xi1 = min(xi0 + 1, 63);
    const int yi0 = min(max((int)yf, 0), 63);
    const int yi1 = min(yi0 + 1, 63);
    const float* base = x0 + (size_t)b * 2097152 + (size_t)c * 4096;
    const float v00 = base[yi0 * 64 + xi0], v01 = base[yi0 * 64 + xi1];
    const float v10 = base[yi1 * 64 + xi0], v11 = base[yi1 * 64 + xi1];
    const float f =
        v00 * (1 - wx) * (1 - wy) + v01 * wx * (1 - wy) +
        v10 * (1 - wx) * wy + v11 * wx * wy;
    const bf16 hb = (bf16)f;
    const size_t addr = ((size_t)b * 256 + n) * 256 + c;
    xs_hi[addr] = hb;
    xs_lo[addr] = (bf16)(f - (float)hb);
}

// ---------------- fused MFMA attention -------------------------------------
// Block = (query row my=blockIdx.x, head, batch).
// v7: two-pass QK^T flash attention, chunk=64, SEPARATE R and P buffers.
//     The 32-reg lg[] accumulator is eliminated: pass 1 computes only the
//     per-row max of qk*0.125 (transient floatx4), pass 2 recomputes the
//     MFMAs, adds bias, exps, writes P immediately. Softmax shift by
//     max(qk*0.125) alone is exact (shift-invariant) and overflow-safe
//     since |bias| << 88. Live set ~70 VGPR -> __launch_bounds__(256,6)
//     (85-reg budget, no spills -- the v6/R5 failure) -> 24 waves/CU.
//     LDS: R[64][66] + P[4][16][72] + wxs = 18.7KB. 7 barriers.
//     Pass 1 runs before bar A, overlapping R staging loads (v6 pattern).
__global__ __launch_bounds__(256, 6) void attn_mfma(
    const bf16* qbfT,               // [b][4096][256]
    const bf16* __restrict__ kT,    // [b][256][256] pixel-major
    const bf16* __restrict__ vb,    // [b][256 c][256 n] channel-major
    const float* __restrict__ pos,
    const float* __restrict__ rpe,  // [4][127][127]
    bf16* obfT)                     // aliases qbfT
{
    __shared__ __align__(16) bf16 Rbuf[64 * 66];     // 8448 B, chunk of R
    __shared__ __align__(16) bf16 Pbuf[4 * 16 * 72]; // 9216 B, wave-private P
    __shared__ float wxs[256];
    const int t = threadIdx.x;
    const int w = t >> 6, l = t & 63;
    const int lr = l & 15, lq = l >> 4;
    const int m_base = blockIdx.x * 64 + w * 16;
    const int my = blockIdx.x;          // query y-row block, constant per block
    const int h = blockIdx.y, b = blockIdx.z;

    // ownership: lane l of wave w owns n_own = (l>>4)*64 + w*16 + (l&15),
    // so staging chunk c row (16w+i) pulls params from own-wave lane c*16+i.
    const int n_own = ((l >> 4) << 6) + w * 16 + (l & 15);
    const float2 pp = *(const float2*)(pos + (b * 256 + n_own) * 2);
    const float yy = (float)my + 63.0f - 31.5f * pp.x;
    const float xo = 63.0f - 31.5f * pp.y;
    const float yfl = floorf(yy);
    const float xfl = floorf(xo);
    const int y0 = min((int)yfl, 126);
    const int y1 = min(y0 + 1, 126);
    const int xb = (int)xfl;            // in [31, 94] -> no lower clamp needed
    const float wy_r = yy - yfl;
    wxs[n_own] = xo - xfl;
    // pack: base0 (<=16096, 14 bits) | x-clamp (126-xb) << 16
    const int u0 = (y0 * 127 + xb) | ((126 - xb) << 16);
    const int u1 = y1 * 127 + xb;

    const float* rp = rpe + h * 16129;

    // Q fragments (early issue)
    const bf16* qrow = qbfT + ((size_t)b * 4096 + m_base + lr) * 256 + h * 64;
    const bf16x8 qf0 = *(const bf16x8*)(qrow + lq * 8);
    const bf16x8 qf1 = *(const bf16x8*)(qrow + 32 + lq * 8);

    float mrun[4] = {-1e30f, -1e30f, -1e30f, -1e30f};
    float srun[4] = {0.0f, 0.0f, 0.0f, 0.0f};
    floatx4 oc[4] = {};
    bf16* plw = Pbuf + w * 16 * 72;     // wave-private P [16 m][72 n]

    for (int c = 0; c < 4; c++) {
        // ---- stage R chunk c: wave w writes rows [16w, 16w+16) ------------
        #pragma unroll
        for (int i = 0; i < 16; i++) {
            const int src = (c << 4) + i;
            const int a0 = __shfl(u0, src);        // uniform src -> readlane
            const int a1 = __shfl(u1, src);
            const float wyi = __shfl(wy_r, src);
            const int xoff = min(l, a0 >> 16);
            const float v0 = rp[(a0 & 0xffff) + xoff];
            const float v1 = rp[a1 + xoff];
            Rbuf[(w * 16 + i) * 66 + l] = (bf16)fmaf(wyi, v1 - v0, v0);
        }
        // tail col 64: owner lanes of this chunk finish their own row
        if ((l >> 4) == c) {
            const int xoff = min(64, u0 >> 16);
            const float v0 = rp[(u0 & 0xffff) + xoff];
            const float v1 = rp[u1 + xoff];
            Rbuf[(w * 16 + (l & 15)) * 66 + 64] = (bf16)fmaf(wy_r, v1 - v0, v0);
        }

        // ---- pass 1: QK^T row max (qk*0.125 only; overlaps staging) -------
        float pmax[4] = {-1e30f, -1e30f, -1e30f, -1e30f};
        #pragma unroll
        for (int nf = 0; nf < 4; nf++) {
            const bf16* krow = kT + ((size_t)b * 256 + c * 64 + nf * 16 + lr) * 256 + h * 64;
            floatx4 a = {};
            a = MFMA16(qf0, *(const bf16x8*)(krow + lq * 8), a);
            a = MFMA16(qf1, *(const bf16x8*)(krow + 32 + lq * 8), a);
            #pragma unroll
            for (int r = 0; r < 4; r++) pmax[r] = fmaxf(pmax[r], a[r]);
        }

        __syncthreads();   // bar A: R chunk (+wxs on c=0) visible to all waves

        // running-max update + rescale
        #pragma unroll
        for (int r = 0; r < 4; r++) {
            float m = pmax[r] * 0.125f;
            #pragma unroll
            for (int off = 1; off < 16; off <<= 1) m = fmaxf(m, __shfl_xor(m, off, 64));
            const float mn = fmaxf(mrun[r], m);
            const float sc = __expf(mrun[r] - mn);
            mrun[r] = mn;
            srun[r] *= sc;
            oc[0][r] *= sc; oc[1][r] *= sc; oc[2][r] *= sc; oc[3][r] *= sc;
        }

        // ---- pass 2: recompute QK, + bias, exp, write P -------------------
        float psum[4] = {0.0f, 0.0f, 0.0f, 0.0f};
        #pragma unroll
        for (int nf = 0; nf < 4; nf++) {
            const bf16* krow = kT + ((size_t)b * 256 + c * 64 + nf * 16 + lr) * 256 + h * 64;
            floatx4 a = {};
            a = MFMA16(qf0, *(const bf16x8*)(krow + lq * 8), a);
            a = MFMA16(qf1, *(const bf16x8*)(krow + 32 + lq * 8), a);
            const int rbuf = nf * 16 + lr;
            const unsigned* rw = (const unsigned*)(Rbuf + rbuf * 66 + w * 16 + lq * 4);
            const unsigned d0 = rw[0], d1 = rw[1], d2 = rw[2];
            float rv[5];
            rv[0] = bflo(d0); rv[1] = bfhi(d0);
            rv[2] = bflo(d1); rv[3] = bfhi(d1);
            rv[4] = bflo(d2);
            const float wxv = wxs[c * 64 + rbuf];
            #pragma unroll
            for (int r = 0; r < 4; r++) {
                const float bias = fmaf(wxv, rv[r + 1] - rv[r], rv[r]);
                const float e = __expf(fmaf(a[r], 0.125f, bias) - mrun[r]);
                psum[r] += e;
                plw[(lq * 4 + r) * 72 + nf * 16 + lr] = (bf16)e;
            }
        }
        #pragma unroll
        for (int r = 0; r < 4; r++) {
            float s = psum[r];
            #pragma unroll
            for (int off = 1; off < 16; off <<= 1) s += __shfl_xor(s, off, 64);
            srun[r] += s;
        }

        // ---- PV over this chunk's 64 k — V straight from global (L2-hot) --
        #pragma unroll
        for (int kf = 0; kf < 2; kf++) {
            const bf16x8 pa = *(const bf16x8*)(plw + lr * 72 + kf * 32 + lq * 8);
            #pragma unroll
            for (int j = 0; j < 4; j++) {
                const bf16x8 vf = *(const bf16x8*)(
                    vb + ((size_t)b * 256 + h * 64 + j * 16 + lr) * 256 + c * 64 + kf * 32 + lq * 8);
                oc[j] = MFMA16(pa, vf, oc[j]);
            }
        }

        if (c < 3) __syncthreads();   // bar B: all bias reads done before restage
    }

    // normalize + output: transpose oc through (dead) wave-private P region,
    // then 2x bf16x8 coalesced stores per lane
    float inv[4];
    #pragma unroll
    for (int r = 0; r < 4; r++) inv[r] = 1.0f / srun[r];

    bf16* ot = plw;                 // [16 m][72 o] within own region
    #pragma unroll
    for (int j = 0; j < 4; j++)
        #pragma unroll
        for (int r = 0; r < 4; r++)
            ot[(lq * 4 + r) * 72 + j * 16 + lr] = (bf16)(oc[j][r] * inv[r]);
    const int mrow = l >> 2, seg = l & 3;
    const bf16x8 ov0 = *(const bf16x8*)(ot + mrow * 72 + seg * 8);
    const bf16x8 ov1 = *(const bf16x8*)(ot + mrow * 72 + (4 + seg) * 8);
    bf16* orow = obfT + ((size_t)b * 4096 + m_base + mrow) * 256 + h * 64;
    *(bf16x8*)(orow + seg * 8) = ov0;
    *(bf16x8*)(orow + (4 + seg) * 8) = ov1;
}

// ---------------- host launcher --------------------------------------------
extern "C" void kernel_launch(void* const* d_in, const int* in_sizes, int n_in,
                              void* d_out, int out_size, void* d_ws, size_t ws_size,
                              hipStream_t stream) {
    const float* x0 = (const float*)d_in[0];
    float* out = (float*)d_out;
    float* ws = (float*)d_ws;
    // ws layout (float units), total ~23.1 MB
    bf16* qbfT  = (bf16*)ws;                   // [8][4096][256] bf16 = 4,194,304 fl
    bf16* xs_hi = (bf16*)(ws + 4194304);       // [8][256][256] bf16  =   262,144 fl
    bf16* xs_lo = xs_hi + 524288;              // [8][256][256] bf16  =   262,144 fl
    bf16* kTb   = (bf16*)(ws + 4718592);       // [8][256][256] bf16  =   262,144 fl
    bf16* vbb   = (bf16*)(ws + 4980736);       // [8][256][256] bf16  =   262,144 fl
    bf16* wbf   = (bf16*)(ws + 5242880);       // 16 x [256][256] bf16=   524,288 fl
    float* pos  = ws + 5767168;                // 4,096 fl
    float* jpart= ws + 5771264;                // 512 fl  (end 5,771,776)

    wconv<<<dim3(64, 8), 256, 0, stream>>>(
        (const float*)d_in[6], (const float*)d_in[8], (const float*)d_in[10],
        (const float*)d_in[12], (const float*)d_in[20], (const float*)d_in[22],
        (const float*)d_in[24], (const float*)d_in[26], wbf);

    for (int pass = 0; pass < 2; pass++) {
        const int pb = 1 + 14 * pass;
        const float* dw_w = (const float*)d_in[pb + 0];
        const float* dw_b = (const float*)d_in[pb + 1];
        const float* ln_g = (const float*)d_in[pb + 2];
        const float* ln_b = (const float*)d_in[pb + 3];
        const float* pw_w = (const float*)d_in[pb + 4];
        const float* bq   = (const float*)d_in[pb + 6];
        const float* bk   = (const float*)d_in[pb + 8];
        const float* bv   = (const float*)d_in[pb + 10];
        const float* bo   = (const float*)d_in[pb + 12];
        const float* rpe  = (const float*)d_in[pb + 13];
        const bf16* wq_h = wbf + (size_t)(pass * 4 + 0) * 65536;
        const bf16* wk_h = wbf + (size_t)(pass * 4 + 1) * 65536;
        const bf16* wv_h = wbf + (size_t)(pass * 4 + 2) * 65536;
        const bf16* wo_h = wbf + (size_t)(pass * 4 + 3) * 65536;
        const bf16* wq_l = wq_h + 8 * 65536;
        const bf16* wk_l = wk_h + 8 * 65536;
        const bf16* wv_l = wv_h + 8 * 65536;
        const bf16* wo_l = wo_h + 8 * 65536;

        gemm_mfma<0><<<dim3(32, 2, 8), 256, 0, stream>>>(
            x0, 4096, 2097152LL, wq_h, wq_l, bq, qbfT, out, nullptr, nullptr);
        offset_kernel<<<dim3(16, 16, 8), 256, 0, stream>>>(
            out, dw_w, dw_b, ln_g, ln_b, pw_w, pos);
        sample_kernel<<<dim3(256, 8), 256, 0, stream>>>(x0, pos, xs_hi, xs_lo);
        gemm_kv<<<dim3(2, 4, 8), 256, 0, stream>>>(
            xs_hi, xs_lo, wk_h, wk_l, wv_h, wv_l, bk, bv, kTb, vbb);
        attn_mfma<<<dim3(64, 4, 8), 256, 0, stream>>>(
            qbfT, kTb, vbb, pos, rpe, qbfT);
        if (pass == 0)
            gemm_mfma<3><<<dim3(32, 2, 8), 256, 0, stream>>>(
                qbfT, 256, 1048576LL, wo_h, wo_l, bo, nullptr, out, nullptr, nullptr);
        else
            gemm_mfma<4><<<dim3(32, 2, 8), 256, 0, stream>>>(
                qbfT, 256, 1048576LL, wo_h, wo_l, bo, nullptr, out, x0, jpart);
    }
    init_kernel<<<8192, 256, 0, stream>>>(x0, out);
    jac_reduce<<<8, 64, 0, stream>>>(jpart, out);
}

// Round 7
// 599.063 us; speedup vs baseline: 1.2583x; 1.2583x over previous
//
#include <hip/hip_runtime.h>
#include <math.h>

typedef __bf16 bf16;
typedef __attribute__((ext_vector_type(8))) __bf16 bf16x8;
typedef __attribute__((ext_vector_type(4))) __bf16 bf16x4;
typedef __attribute__((ext_vector_type(4))) float floatx4;

#define MFMA16(a, b, c) __builtin_amdgcn_mfma_f32_16x16x32_bf16((a), (b), (c), 0, 0, 0)

__device__ __forceinline__ float bflo(unsigned d) {
    unsigned u = d << 16; float f; __builtin_memcpy(&f, &u, 4); return f;
}
__device__ __forceinline__ float bfhi(unsigned d) {
    unsigned u = d & 0xffff0000u; float f; __builtin_memcpy(&f, &u, 4); return f;
}

__device__ __forceinline__ void breduce1(float &a, float* lds, int t) {
    #pragma unroll
    for (int off = 32; off; off >>= 1) a += __shfl_xor(a, off, 64);
    __syncthreads();
    if ((t & 63) == 0) lds[t >> 6] = a;
    __syncthreads();
    a = lds[0] + lds[1] + lds[2] + lds[3];
}

// ---------------- init: copy res lower half --------------------------------
__global__ __launch_bounds__(256) void init_kernel(const float* __restrict__ x0,
                                                   float* __restrict__ out) {
    int fi = blockIdx.x * 256 + threadIdx.x;
    int b = fi >> 18;
    int r = fi & 262143;
    const float4* src = (const float4*)x0;
    float4* dst = (float4*)out;
    dst[(size_t)b * 524288 + r] = src[(size_t)b * 524288 + r];
}

// ---------------- weight fp32 -> bf16 hi/lo pairs (8 matrices) -------------
__global__ __launch_bounds__(256) void wconv(
    const float* __restrict__ w0, const float* __restrict__ w1,
    const float* __restrict__ w2, const float* __restrict__ w3,
    const float* __restrict__ w4, const float* __restrict__ w5,
    const float* __restrict__ w6, const float* __restrict__ w7,
    bf16* __restrict__ dst) {
    const int wi = blockIdx.y;
    const float* src = wi == 0 ? w0 : wi == 1 ? w1 : wi == 2 ? w2 : wi == 3 ? w3
                     : wi == 4 ? w4 : wi == 5 ? w5 : wi == 6 ? w6 : w7;
    const int i = blockIdx.x * 1024 + threadIdx.x * 4;
    const float4 v = *(const float4*)(src + i);
    bf16x4 h, l;
    #pragma unroll
    for (int j = 0; j < 4; j++) {
        const float f = ((const float*)&v)[j];
        const bf16 hb = (bf16)f;
        h[j] = hb;
        l[j] = (bf16)(f - (float)hb);
    }
    *(bf16x4*)(dst + (size_t)wi * 65536 + i) = h;
    *(bf16x4*)(dst + (size_t)(8 + wi) * 65536 + i) = l;
}

// ---------------- split-precision MFMA GEMM --------------------------------
// D[n][o] = A[n][k] * W[o][k]^T + bias.  tile 128n x 128o, K=256 in 8x32.
// MODE 0: A fp32 [k][n] staged+split; out q fp32 + qbfT bf16.
// MODE 3: A bf16 [n][k]; out s fp32 (upper half).
// MODE 4: A bf16 [n][k]; fused res = x0*exp(s)+t write + jac partial.
template <int MODE>
__global__ __launch_bounds__(256) void gemm_mfma(
    const void* __restrict__ Aptr, int ldA, long long bsA,
    const bf16* __restrict__ Whi, const bf16* __restrict__ Wlo,
    const float* __restrict__ bias,
    bf16* __restrict__ outb,
    float* outf,
    const float* __restrict__ x0full,
    float* __restrict__ jpart)
{
    constexpr bool ASPLIT = (MODE <= 2);
    __shared__ __align__(16) bf16 As_hi[128 * 40];
    __shared__ __align__(16) bf16 As_lo[ASPLIT ? 128 * 40 : 1];
    __shared__ __align__(16) bf16 Bs_hi[128 * 40];
    __shared__ __align__(16) bf16 Bs_lo[128 * 40];
    __shared__ float red[4];
    const int t = threadIdx.x;
    const int b = blockIdx.z;
    const int n0 = blockIdx.x * 128;
    const int o0 = blockIdx.y * 128;
    const int w = t >> 6, l = t & 63;
    const int wr = w & 1, wc = w >> 1;
    const int lr = l & 15, lq = l >> 4;

    floatx4 acc[4][4] = {};

    for (int kb = 0; kb < 8; kb++) {
        if (ASPLIT) {
            const float* Af = (const float*)Aptr + (size_t)b * bsA;
            #pragma unroll
            for (int s = 0; s < 4; s++) {
                const int kk = s * 8 + (t >> 5);
                const int n = (t & 31) * 4;
                const float4 v = *(const float4*)(Af + (size_t)(kb * 32 + kk) * ldA + n0 + n);
                #pragma unroll
                for (int j = 0; j < 4; j++) {
                    const float f = ((const float*)&v)[j];
                    const bf16 hb = (bf16)f;
                    As_hi[(n + j) * 40 + kk] = hb;
                    As_lo[(n + j) * 40 + kk] = (bf16)(f - (float)hb);
                }
            }
        } else {
            const bf16* Ab = (const bf16*)Aptr + (size_t)b * bsA;
            #pragma unroll
            for (int s = 0; s < 2; s++) {
                const int idx = t + 256 * s;
                const int row = idx >> 2, seg = idx & 3;
                *(bf16x8*)(As_hi + row * 40 + seg * 8) =
                    *(const bf16x8*)(Ab + (size_t)(n0 + row) * 256 + kb * 32 + seg * 8);
            }
        }
        #pragma unroll
        for (int s = 0; s < 2; s++) {
            const int idx = t + 256 * s;
            const int row = idx >> 2, seg = idx & 3;
            *(bf16x8*)(Bs_hi + row * 40 + seg * 8) =
                *(const bf16x8*)(Whi + (size_t)(o0 + row) * 256 + kb * 32 + seg * 8);
            *(bf16x8*)(Bs_lo + row * 40 + seg * 8) =
                *(const bf16x8*)(Wlo + (size_t)(o0 + row) * 256 + kb * 32 + seg * 8);
        }
        __syncthreads();
        bf16x8 ah[4], al[4], bh[4], bl[4];
        #pragma unroll
        for (int f = 0; f < 4; f++) {
            ah[f] = *(const bf16x8*)(As_hi + (wr * 64 + f * 16 + lr) * 40 + lq * 8);
            if (ASPLIT)
                al[f] = *(const bf16x8*)(As_lo + (wr * 64 + f * 16 + lr) * 40 + lq * 8);
            bh[f] = *(const bf16x8*)(Bs_hi + (wc * 64 + f * 16 + lr) * 40 + lq * 8);
            bl[f] = *(const bf16x8*)(Bs_lo + (wc * 64 + f * 16 + lr) * 40 + lq * 8);
        }
        #pragma unroll
        for (int i = 0; i < 4; i++)
            #pragma unroll
            for (int j = 0; j < 4; j++) {
                acc[i][j] = MFMA16(ah[i], bh[j], acc[i][j]);
                acc[i][j] = MFMA16(ah[i], bl[j], acc[i][j]);
                if (ASPLIT) acc[i][j] = MFMA16(al[i], bh[j], acc[i][j]);
            }
        __syncthreads();
    }

    float ssum = 0.0f;
    #pragma unroll
    for (int i = 0; i < 4; i++) {
        #pragma unroll
        for (int j = 0; j < 4; j++) {
            const int o_g = o0 + wc * 64 + j * 16 + lr;
            const int n_b = n0 + wr * 64 + i * 16 + lq * 4;
            const float bia = bias[o_g];
            floatx4 val = acc[i][j];
            val[0] += bia; val[1] += bia; val[2] += bia; val[3] += bia;
            if (MODE == 0) {
                *(floatx4*)(outf + (size_t)b * 2097152 + (size_t)o_g * 4096 + n_b) = val;
                #pragma unroll
                for (int r = 0; r < 4; r++)
                    outb[((size_t)b * 4096 + n_b + r) * 256 + o_g] = (bf16)val[r];
            } else {
                const size_t addr = (size_t)b * 2097152 + (size_t)(256 + o_g) * 4096 + n_b;
                if (MODE == 3) {
                    *(floatx4*)(outf + addr) = val;
                } else {
                    const floatx4 s4 = *(const floatx4*)(outf + addr);
                    const floatx4 x4 = *(const floatx4*)(x0full + addr);
                    floatx4 res;
                    #pragma unroll
                    for (int r = 0; r < 4; r++) res[r] = x4[r] * __expf(s4[r]) + val[r];
                    *(floatx4*)(outf + addr) = res;
                    ssum += s4[0] + s4[1] + s4[2] + s4[3];
                }
            }
        }
    }
    if (MODE == 4) {
        breduce1(ssum, red, t);
        if (t == 0) jpart[b * 64 + blockIdx.y * 32 + blockIdx.x] = ssum;
    }
}

// ---------------- merged K+V GEMM (pre-split bf16 A) -----------------------
// v2: 64n x 64o tiles for 4x block parallelism (256 blocks vs 64 -> this tiny
// GEMM was ~1 wave/CU, pure latency exposure).
// A = xs hi/lo [b][n 256][c 256].  grid (4 n-tiles, 8 = {kv, o-tile}, 8 b)
__global__ __launch_bounds__(256) void gemm_kv(
    const bf16* __restrict__ xs_hi, const bf16* __restrict__ xs_lo,
    const bf16* __restrict__ wkh, const bf16* __restrict__ wkl,
    const bf16* __restrict__ wvh, const bf16* __restrict__ wvl,
    const float* __restrict__ bk, const float* __restrict__ bv,
    bf16* __restrict__ kT, bf16* __restrict__ vbuf)
{
    __shared__ __align__(16) bf16 As_hi[64 * 40];
    __shared__ __align__(16) bf16 As_lo[64 * 40];
    __shared__ __align__(16) bf16 Bs_hi[64 * 40];
    __shared__ __align__(16) bf16 Bs_lo[64 * 40];
    const int t = threadIdx.x;
    const int b = blockIdx.z;
    const int n0 = blockIdx.x * 64;
    const int kv = blockIdx.y >> 2;
    const int o0 = (blockIdx.y & 3) * 64;
    const bf16* Whi = kv ? wvh : wkh;
    const bf16* Wlo = kv ? wvl : wkl;
    const float* bias = kv ? bv : bk;
    const int w = t >> 6, l = t & 63;
    const int wr = w & 1, wc = w >> 1;
    const int lr = l & 15, lq = l >> 4;

    floatx4 acc[2][2] = {};

    for (int kb = 0; kb < 8; kb++) {
        {
            const int row = t >> 2, seg = t & 3;   // 64 rows x 4 segs = 256
            const size_t asrc = ((size_t)b * 256 + n0 + row) * 256 + kb * 32 + seg * 8;
            *(bf16x8*)(As_hi + row * 40 + seg * 8) = *(const bf16x8*)(xs_hi + asrc);
            *(bf16x8*)(As_lo + row * 40 + seg * 8) = *(const bf16x8*)(xs_lo + asrc);
            const size_t bsrc = (size_t)(o0 + row) * 256 + kb * 32 + seg * 8;
            *(bf16x8*)(Bs_hi + row * 40 + seg * 8) = *(const bf16x8*)(Whi + bsrc);
            *(bf16x8*)(Bs_lo + row * 40 + seg * 8) = *(const bf16x8*)(Wlo + bsrc);
        }
        __syncthreads();
        bf16x8 ah[2], al[2], bh[2], bl[2];
        #pragma unroll
        for (int f = 0; f < 2; f++) {
            ah[f] = *(const bf16x8*)(As_hi + (wr * 32 + f * 16 + lr) * 40 + lq * 8);
            al[f] = *(const bf16x8*)(As_lo + (wr * 32 + f * 16 + lr) * 40 + lq * 8);
            bh[f] = *(const bf16x8*)(Bs_hi + (wc * 32 + f * 16 + lr) * 40 + lq * 8);
            bl[f] = *(const bf16x8*)(Bs_lo + (wc * 32 + f * 16 + lr) * 40 + lq * 8);
        }
        #pragma unroll
        for (int i = 0; i < 2; i++)
            #pragma unroll
            for (int j = 0; j < 2; j++) {
                acc[i][j] = MFMA16(ah[i], bh[j], acc[i][j]);
                acc[i][j] = MFMA16(ah[i], bl[j], acc[i][j]);
                acc[i][j] = MFMA16(al[i], bh[j], acc[i][j]);
            }
        __syncthreads();
    }

    #pragma unroll
    for (int i = 0; i < 2; i++) {
        #pragma unroll
        for (int j = 0; j < 2; j++) {
            const int o_g = o0 + wc * 32 + j * 16 + lr;
            const int n_b = n0 + wr * 32 + i * 16 + lq * 4;
            const float bia = bias[o_g];
            floatx4 val = acc[i][j];
            val[0] += bia; val[1] += bia; val[2] += bia; val[3] += bia;
            if (kv == 0) {
                #pragma unroll
                for (int r = 0; r < 4; r++)
                    kT[((size_t)b * 256 + n_b + r) * 256 + o_g] = (bf16)val[r];
            } else {
                bf16x4 pv;
                pv[0] = (bf16)val[0]; pv[1] = (bf16)val[1];
                pv[2] = (bf16)val[2]; pv[3] = (bf16)val[3];
                *(bf16x4*)(vbuf + ((size_t)b * 256 + o_g) * 256 + n_b) = pv;
            }
        }
    }
}

// ---------------- jac finalize ---------------------------------------------
__global__ __launch_bounds__(64) void jac_reduce(const float* __restrict__ jpart,
                                                 float* __restrict__ out) {
    const int b = blockIdx.x, t = threadIdx.x;
    float v = jpart[b * 64 + t];
    #pragma unroll
    for (int off = 32; off; off >>= 1) v += __shfl_xor(v, off, 64);
    if (t == 0) out[16777216 + b] = v;
}

// ---------------- offset branch (q fp32 lives in out-lower) ----------------
__global__ __launch_bounds__(256) void offset_kernel(
    const float* __restrict__ q,
    const float* __restrict__ dw_w, const float* __restrict__ dw_b,
    const float* __restrict__ ln_g, const float* __restrict__ ln_b,
    const float* __restrict__ pw_w,
    float* __restrict__ pos)
{
    __shared__ float red[8];
    const int wk = blockIdx.x, hk = blockIdx.y, b = blockIdx.z;
    const int c = threadIdx.x;
    const float* qp = q + (size_t)b * 2097152 + (size_t)c * 4096 + (hk * 4) * 64 + wk * 4;
    float accv = dw_b[c];
    #pragma unroll
    for (int p = 0; p < 4; p++) {
        const float4 r = *(const float4*)(qp + p * 64);
        const float4 w = *(const float4*)(dw_w + c * 16 + p * 4);
        accv += r.x * w.x + r.y * w.y + r.z * w.z + r.w * w.w;
    }
    float a = accv, sq = accv * accv;
    #pragma unroll
    for (int off = 32; off; off >>= 1) {
        a += __shfl_xor(a, off, 64);
        sq += __shfl_xor(sq, off, 64);
    }
    __syncthreads();
    if ((c & 63) == 0) { red[c >> 6] = a; red[4 + (c >> 6)] = sq; }
    __syncthreads();
    a = red[0] + red[1] + red[2] + red[3];
    sq = red[4] + red[5] + red[6] + red[7];
    const float mu = a * (1.0f / 256.0f);
    const float var = sq * (1.0f / 256.0f) - mu * mu;
    float nrm = (accv - mu) * rsqrtf(var + 1e-5f) * ln_g[c] + ln_b[c];
    const float act = 0.5f * nrm * (1.0f + erff(nrm * 0.70710678118654752f));
    float v0 = pw_w[c] * act;
    float v1 = pw_w[256 + c] * act;
    #pragma unroll
    for (int off = 32; off; off >>= 1) {
        v0 += __shfl_xor(v0, off, 64);
        v1 += __shfl_xor(v1, off, 64);
    }
    __syncthreads();
    if ((c & 63) == 0) { red[c >> 6] = v0; red[4 + (c >> 6)] = v1; }
    __syncthreads();
    if (c == 0) {
        v0 = red[0] + red[1] + red[2] + red[3];
        v1 = red[4] + red[5] + red[6] + red[7];
        const float refy = (0.5f + hk) * (2.0f / 15.0f) - 1.0f;
        const float refx = (0.5f + wk) * (2.0f / 15.0f) - 1.0f;
        const float py = fminf(fmaxf(v0 + refy, -1.0f), 1.0f);
        const float px = fminf(fmaxf(v1 + refx, -1.0f), 1.0f);
        const int n = hk * 16 + wk;
        pos[(b * 256 + n) * 2] = py;
        pos[(b * 256 + n) * 2 + 1] = px;
    }
}

// ---------------- bilinear sample -> xs bf16 hi/lo [b][n][c] ---------------
__global__ __launch_bounds__(256) void sample_kernel(
    const float* __restrict__ x0,
    const float* __restrict__ pos,
    bf16* __restrict__ xs_hi,
    bf16* __restrict__ xs_lo)
{
    const int c = threadIdx.x, n = blockIdx.x, b = blockIdx.y;
    const float py = pos[(b * 256 + n) * 2];
    const float px = pos[(b * 256 + n) * 2 + 1];
    const float x = (px + 1.0f) * 31.5f;
    const float y = (py + 1.0f) * 31.5f;
    const float xf = floorf(x), yf = floorf(y);
    const float wx = x - xf, wy = y - yf;
    const int xi0 = min(max((int)xf, 0), 63);
    const int xi1 = min(xi0 + 1, 63);
    const int yi0 = min(max((int)yf, 0), 63);
    const int yi1 = min(yi0 + 1, 63);
    const float* base = x0 + (size_t)b * 2097152 + (size_t)c * 4096;
    const float v00 = base[yi0 * 64 + xi0], v01 = base[yi0 * 64 + xi1];
    const float v10 = base[yi1 * 64 + xi0], v11 = base[yi1 * 64 + xi1];
    const float f =
        v00 * (1 - wx) * (1 - wy) + v01 * wx * (1 - wy) +
        v10 * (1 - wx) * wy + v11 * wx * wy;
    const bf16 hb = (bf16)f;
    const size_t addr = ((size_t)b * 256 + n) * 256 + c;
    xs_hi[addr] = hb;
    xs_lo[addr] = (bf16)(f - (float)hb);
}

// ---------------- fused MFMA attention -------------------------------------
// Block = (query row my=blockIdx.x, head, batch).
// v3 (reverted): the measured optimum for this structure (85.5us, VGPR 64,
// no spills). R4-R6 established: direct rpe gather breaks L2 (lane-scatter),
// and any occupancy push past 4 blocks/CU spills (live set > 85 regs).
__global__ __launch_bounds__(256, 4) void attn_mfma(
    const bf16* qbfT,               // [b][4096][256]
    const bf16* __restrict__ kT,    // [b][256][256] pixel-major
    const bf16* __restrict__ vb,    // [b][256 c][256 n] channel-major
    const float* __restrict__ pos,
    const float* __restrict__ rpe,
    bf16* obfT)                     // aliases qbfT
{
    __shared__ __align__(16) bf16 pl[16896];   // R: [256 n][66] then P: [4][16][264]
    __shared__ float wxs[256];
    const int t = threadIdx.x;
    const int w = t >> 6, l = t & 63;
    const int lr = l & 15, lq = l >> 4;
    const int m_base = blockIdx.x * 64 + w * 16;
    const int my = blockIdx.x;          // m>>6, constant per block
    const int h = blockIdx.y, b = blockIdx.z;

    // per-n scalar setup: this thread owns n = t (wave w owns n in [64w, 64w+64))
    const float2 pp = *(const float2*)(pos + (b * 256 + t) * 2);
    const float yy = (float)my + 63.0f - 31.5f * pp.x;
    const float xo = 63.0f - 31.5f * pp.y;
    const float yfl = floorf(yy);
    const float wy_r = yy - yfl;
    const int y0 = min((int)yfl, 126);
    const int o0_r = y0 * 127;
    const int o1_r = min(y0 + 1, 126) * 127;
    const int xb_r = (int)floorf(xo);
    wxs[t] = xo - (float)xb_r;

    const float* rp = rpe + h * 16129;

    // Q fragments (issue early; overlap with R staging)
    const bf16* qrow = qbfT + ((size_t)b * 4096 + m_base + lr) * 256 + h * 64;
    const bf16x8 qf0 = *(const bf16x8*)(qrow + lq * 8);
    const bf16x8 qf1 = *(const bf16x8*)(qrow + 32 + lq * 8);

    // stage R (y-blended rpe rows): wave w covers its own n range, lane l = x
    #pragma unroll 8
    for (int i = 0; i < 64; i++) {
        const int xb = __shfl(xb_r, i);        // uniform index -> v_readlane
        const float wy = __shfl(wy_r, i);
        const int o0 = __shfl(o0_r, i);
        const int o1 = __shfl(o1_r, i);
        const int xj = min(xb + l, 126);
        const float v0 = rp[o0 + xj];
        const float v1 = rp[o1 + xj];
        pl[(w * 64 + i) * 66 + l] = (bf16)fmaf(wy, v1 - v0, v0);
    }
    // tail x=64: each lane finishes its own n = t (fully parallel, no branch)
    {
        const int xe = min(xb_r + 64, 126);
        const float e0 = rp[o0_r + xe];
        const float e1 = rp[o1_r + xe];
        pl[t * 66 + 64] = (bf16)fmaf(wy_r, e1 - e0, e0);
    }

    // QK^T — K fragments straight from global (tile is L2-hot)
    floatx4 lg[16];
    #pragma unroll
    for (int nf = 0; nf < 16; nf++) {
        const bf16* krow = kT + ((size_t)b * 256 + nf * 16 + lr) * 256 + h * 64;
        const bf16x8 k0 = *(const bf16x8*)(krow + lq * 8);
        const bf16x8 k1 = *(const bf16x8*)(krow + 32 + lq * 8);
        floatx4 a = {};
        a = MFMA16(qf0, k0, a);
        a = MFMA16(qf1, k1, a);
        lg[nf] = a;
    }

    // V prefetch kf in {0,1}: latency hides under bias+softmax
    bf16x8 vpre[2][4];
    #pragma unroll
    for (int kf = 0; kf < 2; kf++)
        #pragma unroll
        for (int j = 0; j < 4; j++)
            vpre[kf][j] = *(const bf16x8*)(
                vb + ((size_t)b * 256 + h * 64 + j * 16 + lr) * 256 + kf * 32 + lq * 8);

    __syncthreads();   // R + wxs staged; cross-wave reads begin

    // bias from R: thread covers m-cols mx = w*16+lq*4 .. +3 (4-byte aligned dwords)
    #pragma unroll
    for (int nf = 0; nf < 16; nf++) {
        const int n = nf * 16 + lr;
        const unsigned* rw = (const unsigned*)(pl + n * 66 + w * 16 + lq * 4);
        const unsigned d0 = rw[0], d1 = rw[1], d2 = rw[2];
        float rv[5];
        rv[0] = bflo(d0); rv[1] = bfhi(d0);
        rv[2] = bflo(d1); rv[3] = bfhi(d1);
        rv[4] = bflo(d2);
        const float wxv = wxs[n];
        #pragma unroll
        for (int r = 0; r < 4; r++)
            lg[nf][r] = lg[nf][r] * 0.125f + (rv[r] + wxv * (rv[r + 1] - rv[r]));
    }

    // softmax per row (16 lanes share a row)
    float mx[4], inv[4];
    #pragma unroll
    for (int r = 0; r < 4; r++) {
        float m = -1e30f;
        #pragma unroll
        for (int nf = 0; nf < 16; nf++) m = fmaxf(m, lg[nf][r]);
        #pragma unroll
        for (int off = 1; off < 16; off <<= 1) m = fmaxf(m, __shfl_xor(m, off, 64));
        mx[r] = m;
    }
    #pragma unroll
    for (int r = 0; r < 4; r++) {
        float s = 0.0f;
        #pragma unroll
        for (int nf = 0; nf < 16; nf++) {
            const float e = __expf(lg[nf][r] - mx[r]);
            lg[nf][r] = e;
            s += e;
        }
        #pragma unroll
        for (int off = 1; off < 16; off <<= 1) s += __shfl_xor(s, off, 64);
        inv[r] = 1.0f / s;
    }

    __syncthreads();   // all waves done reading R (pl) before P overwrites it

    // P (scaled) -> bf16 LDS, wave-private [16 m][264 n]
    bf16* plw = pl + w * 16 * 264;
    #pragma unroll
    for (int nf = 0; nf < 16; nf++)
        #pragma unroll
        for (int r = 0; r < 4; r++)
            plw[(lq * 4 + r) * 264 + nf * 16 + lr] = (bf16)(lg[nf][r] * inv[r]);

    // PV — P from own-wave LDS (no barrier needed), V from prefetch/global
    floatx4 oc[4] = {};
    #pragma unroll
    for (int kf = 0; kf < 8; kf++) {
        const bf16x8 pa = *(const bf16x8*)(plw + lr * 264 + kf * 32 + lq * 8);
        #pragma unroll
        for (int j = 0; j < 4; j++) {
            const bf16x8 vf = (kf < 2) ? vpre[kf][j] : *(const bf16x8*)(
                vb + ((size_t)b * 256 + h * 64 + j * 16 + lr) * 256 + kf * 32 + lq * 8);
            oc[j] = MFMA16(pa, vf, oc[j]);
        }
    }

    // output: transpose oc through the (dead) wave-private P region, then
    // 2x bf16x8 coalesced stores per lane
    bf16* ot = plw;                 // [16 m][72 o], 144B rows (16B aligned)
    #pragma unroll
    for (int j = 0; j < 4; j++)
        #pragma unroll
        for (int r = 0; r < 4; r++)
            ot[(lq * 4 + r) * 72 + j * 16 + lr] = (bf16)oc[j][r];
    const int mrow = l >> 2, seg = l & 3;
    const bf16x8 ov0 = *(const bf16x8*)(ot + mrow * 72 + seg * 8);
    const bf16x8 ov1 = *(const bf16x8*)(ot + mrow * 72 + (4 + seg) * 8);
    bf16* orow = obfT + ((size_t)b * 4096 + m_base + mrow) * 256 + h * 64;
    *(bf16x8*)(orow + seg * 8) = ov0;
    *(bf16x8*)(orow + (4 + seg) * 8) = ov1;
}

// ---------------- host launcher --------------------------------------------
extern "C" void kernel_launch(void* const* d_in, const int* in_sizes, int n_in,
                              void* d_out, int out_size, void* d_ws, size_t ws_size,
                              hipStream_t stream) {
    const float* x0 = (const float*)d_in[0];
    float* out = (float*)d_out;
    float* ws = (float*)d_ws;
    // ws layout (float units), total ~23.1 MB
    bf16* qbfT  = (bf16*)ws;                   // [8][4096][256] bf16 = 4,194,304 fl
    bf16* xs_hi = (bf16*)(ws + 4194304);       // [8][256][256] bf16  =   262,144 fl
    bf16* xs_lo = xs_hi + 524288;              // [8][256][256] bf16  =   262,144 fl
    bf16* kTb   = (bf16*)(ws + 4718592);       // [8][256][256] bf16  =   262,144 fl
    bf16* vbb   = (bf16*)(ws + 4980736);       // [8][256][256] bf16  =   262,144 fl
    bf16* wbf   = (bf16*)(ws + 5242880);       // 16 x [256][256] bf16=   524,288 fl
    float* pos  = ws + 5767168;                // 4,096 fl
    float* jpart= ws + 5771264;                // 512 fl  (end 5,771,776)

    wconv<<<dim3(64, 8), 256, 0, stream>>>(
        (const float*)d_in[6], (const float*)d_in[8], (const float*)d_in[10],
        (const float*)d_in[12], (const float*)d_in[20], (const float*)d_in[22],
        (const float*)d_in[24], (const float*)d_in[26], wbf);

    for (int pass = 0; pass < 2; pass++) {
        const int pb = 1 + 14 * pass;
        const float* dw_w = (const float*)d_in[pb + 0];
        const float* dw_b = (const float*)d_in[pb + 1];
        const float* ln_g = (const float*)d_in[pb + 2];
        const float* ln_b = (const float*)d_in[pb + 3];
        const float* pw_w = (const float*)d_in[pb + 4];
        const float* bq   = (const float*)d_in[pb + 6];
        const float* bk   = (const float*)d_in[pb + 8];
        const float* bv   = (const float*)d_in[pb + 10];
        const float* bo   = (const float*)d_in[pb + 12];
        const float* rpe  = (const float*)d_in[pb + 13];
        const bf16* wq_h = wbf + (size_t)(pass * 4 + 0) * 65536;
        const bf16* wk_h = wbf + (size_t)(pass * 4 + 1) * 65536;
        const bf16* wv_h = wbf + (size_t)(pass * 4 + 2) * 65536;
        const bf16* wo_h = wbf + (size_t)(pass * 4 + 3) * 65536;
        const bf16* wq_l = wq_h + 8 * 65536;
        const bf16* wk_l = wk_h + 8 * 65536;
        const bf16* wv_l = wv_h + 8 * 65536;
        const bf16* wo_l = wo_h + 8 * 65536;

        gemm_mfma<0><<<dim3(32, 2, 8), 256, 0, stream>>>(
            x0, 4096, 2097152LL, wq_h, wq_l, bq, qbfT, out, nullptr, nullptr);
        offset_kernel<<<dim3(16, 16, 8), 256, 0, stream>>>(
            out, dw_w, dw_b, ln_g, ln_b, pw_w, pos);
        sample_kernel<<<dim3(256, 8), 256, 0, stream>>>(x0, pos, xs_hi, xs_lo);
        gemm_kv<<<dim3(4, 8, 8), 256, 0, stream>>>(
            xs_hi, xs_lo, wk_h, wk_l, wv_h, wv_l, bk, bv, kTb, vbb);
        attn_mfma<<<dim3(64, 4, 8), 256, 0, stream>>>(
            qbfT, kTb, vbb, pos, rpe, qbfT);
        if (pass == 0)
            gemm_mfma<3><<<dim3(32, 2, 8), 256, 0, stream>>>(
                qbfT, 256, 1048576LL, wo_h, wo_l, bo, nullptr, out, nullptr, nullptr);
        else
            gemm_mfma<4><<<dim3(32, 2, 8), 256, 0, stream>>>(
                qbfT, 256, 1048576LL, wo_h, wo_l, bo, nullptr, out, x0, jpart);
    }
    init_kernel<<<8192, 256, 0, stream>>>(x0, out);
    jac_reduce<<<8, 64, 0, stream>>>(jpart, out);
}